// Round 18
// baseline (268.678 us; speedup 1.0000x reference)
//
#include <hip/hip_runtime.h>
#include <math.h>

#define Cc 96
#define C4 384
#define Hh 40
#define Ww 40
#define Pp 1600
#define Ss 100
#define S4 25
#define Nn 9216   // 96*96

// d_out offsets (floats): s, ph, bt, pi
#define OFF_S  0
#define OFF_PH 153600
#define OFF_BT 15513600
#define OFF_PI 15667200

// ws offsets (floats)
#define WS_W1T   0
#define WS_W2T   36864
#define WS_RATIO 73728
#define WS_SC    WS_RATIO            // [c][p] dwconv(signal)+b, MFMA path only
#define WS_BC    (WS_RATIO + 153600) // [c][p] dwconv(beta)+b
#define WS_SCALE 688128
#define WS_RH    841728     // ushort[1600][384] -> 307200 float slots each
#define WS_RM    1148928
#define WS_RL    1456128
#define WS_GH    1763328    // ushort[9216][384] -> 1769472 float slots each
#define WS_GM    3532800
#define WS_GL    5302272
#define WS_T     7071744    // f32 T buffer (full or chunk)
#define CHUNK    640
#define WS_NEED_CHUNK (WS_T + CHUNK*Nn)   // 12969984 floats (51.9 MB)
#define WS_NEED_FULL  (WS_T + Pp*Nn)      // 21817344 floats (87.3 MB)

typedef __attribute__((ext_vector_type(8))) short bf16x8_t;
typedef __attribute__((ext_vector_type(4))) float f32x4_t;

__device__ inline float4 f4fma(float4 a, float w, float4 b){
  a.x += w*b.x; a.y += w*b.y; a.z += w*b.z; a.w += w*b.w; return a;
}
__device__ inline unsigned short bf16_rne(float x){
  unsigned int u = __float_as_uint(x);
  return (unsigned short)((u + 0x7fffu + ((u>>16)&1u)) >> 16);
}
__device__ inline float bf16_to_f(unsigned short h){
  return __uint_as_float(((unsigned int)h)<<16);
}
__device__ inline void gload16(const void* g, void* l){
  __builtin_amdgcn_global_load_lds(
    (const __attribute__((address_space(1))) void*)g,
    (__attribute__((address_space(3))) void*)l, 16, 0, 0);
}

// ---- K0: transpose w1 -> w1T[c][o], w2 -> w2T[o][c] ----
__global__ __launch_bounds__(256) void k0_transpose(const float* __restrict__ w1,
    const float* __restrict__ w2, float* __restrict__ ws){
  int idx = blockIdx.x*256 + threadIdx.x;
  if (idx < C4*Cc){
    int o = idx/Cc, c = idx%Cc;
    ws[WS_W1T + c*C4 + o] = w1[idx];
    int c2 = idx/C4, o2 = idx%C4;
    ws[WS_W2T + o2*Cc + c2] = w2[idx];
  }
}

// ---- K0g3: G[i*96+j][o] = w2[i][o]*w1T[j][o], 3 bf16 levels ----
__global__ __launch_bounds__(256) void k0g3(const float* __restrict__ w2,
    float* __restrict__ wsm){
  int i = blockIdx.x;
  int base = blockIdx.y * (Cc*C4/8);
  unsigned short* gh = (unsigned short*)(wsm + WS_GH);
  unsigned short* gm = (unsigned short*)(wsm + WS_GM);
  unsigned short* gl = (unsigned short*)(wsm + WS_GL);
  for (int k = threadIdx.x; k < Cc*C4/8; k += 256){
    int idx = base + k;
    int j = idx / C4, o = idx % C4;
    float g = w2[i*C4 + o] * wsm[WS_W1T + j*C4 + o];
    unsigned short h = bf16_rne(g);           float fh = bf16_to_f(h);
    unsigned short m = bf16_rne(g - fh);      float fm2 = bf16_to_f(m);
    unsigned short lo = bf16_rne(g - fh - fm2);
    size_t off = ((size_t)i*Cc + j)*C4 + o;
    gh[off] = h; gm[off] = m; gl[off] = lo;
  }
}

// ---- K1a: dwconv7x7 of signal & beta, coalesced (lanes = pixels) ----
__global__ __launch_bounds__(256) void k1a_dwconv(const float* __restrict__ signal,
    const float* __restrict__ beta, const float* __restrict__ dw_w,
    const float* __restrict__ dw_b, float* __restrict__ ws){
  int c = blockIdx.x;
  int pp = blockIdx.y*256 + threadIdx.x;
  if (pp >= Pp) return;
  int h = pp / Ww, w = pp % Ww;
  float wk[49];
  #pragma unroll
  for (int i=0; i<49; i++) wk[i] = dw_w[c*49 + i];   // wave-uniform
  const float* sb = signal + (size_t)c*Pp;
  const float* bb = beta   + (size_t)c*Pp;
  float sc = 0.f, btc = 0.f;
  #pragma unroll
  for (int ky=0; ky<7; ky++){
    int y = h + ky - 3;
    if (y >= 0 && y < Hh){
      #pragma unroll
      for (int kx=0; kx<7; kx++){
        int x = w + kx - 3;
        if (x >= 0 && x < Ww){
          float wv = wk[ky*7+kx];
          sc  = fmaf(wv, sb[y*Ww + x], sc);
          btc = fmaf(wv, bb[y*Ww + x], btc);
        }
      }
    }
  }
  float b = dw_b[c];
  ws[WS_SC + (size_t)c*Pp + pp] = sc + b;
  ws[WS_BC + (size_t)c*Pp + pp] = btc + b;
}

// ---- K1: scalar path (s, bt), 384 threads; dwconv read from WS_SC/WS_BC ----
__global__ __launch_bounds__(384) void k1_scalar(
    const float* __restrict__ signal, const float* __restrict__ beta,
    const float* __restrict__ ln_w, const float* __restrict__ ln_b,
    const float* __restrict__ b1, const float* __restrict__ b2,
    const float* __restrict__ gamma, float* __restrict__ ws,
    float* __restrict__ out){
  int p = blockIdx.x, t = threadIdx.x;
  int g = t / 96, c = t - g*96;
  __shared__ float scp[4][96], btp[4][96];
  __shared__ float sl[Cc], bl[Cc], g1[C4], g2[C4], red[2];

  float sc = 0.f, btc = 0.f;
  if (t < 96){
    sc  = ws[WS_SC + (size_t)t*Pp + p];
    btc = ws[WS_BC + (size_t)t*Pp + p];
    scp[0][t] = sc;
  }
  __syncthreads();
  if (t < 64){
    float x = scp[0][t] + (t < 32 ? scp[0][64+t] : 0.f);
    #pragma unroll
    for (int off=32; off>0; off>>=1) x += __shfl_xor(x, off);
    if (t == 0) red[0] = x * (1.f/Cc);
  }
  __syncthreads();
  float u = red[0];
  if (t < 96){ float d = sc - u; scp[1][t] = d*d; }
  __syncthreads();
  if (t < 64){
    float x = scp[1][t] + (t < 32 ? scp[1][64+t] : 0.f);
    #pragma unroll
    for (int off=32; off>0; off>>=1) x += __shfl_xor(x, off);
    if (t == 0) red[1] = x * (1.f/Cc);
  }
  __syncthreads();
  float inv = 1.0f / sqrtf(red[1] + 1e-6f);
  if (t < 96){
    float scl = ln_w[t] * inv;
    ws[WS_SCALE + p*Cc + t] = scl;
    sl[t] = (sc - u)*inv*ln_w[t] + ln_b[t];
    bl[t] = btc*scl + (ln_b[t] - u*scl);
  }
  __syncthreads();
  // pwconv1: thread t = o (coalesced w1T column reads)
  {
    float a = b1[t], e = b1[t];
    const float* wp = ws + WS_W1T + t;
    for (int cc=0; cc<Cc; cc++){
      float wv = wp[cc*C4];
      a = fmaf(wv, sl[cc], a);
      e = fmaf(wv, bl[cc], e);
    }
    float x = a;
    float gg = 0.5f*x*(1.f + erff(x*0.70710678118654752f));
    float r = (fabsf(x) > 1e-6f) ? gg/x : 0.f;
    unsigned short* rh = (unsigned short*)(ws + WS_RH);
    unsigned short* rm = (unsigned short*)(ws + WS_RM);
    unsigned short* rl = (unsigned short*)(ws + WS_RL);
    unsigned short hh = bf16_rne(r);          float fh = bf16_to_f(hh);
    unsigned short hm = bf16_rne(r - fh);     float fm2 = bf16_to_f(hm);
    unsigned short hl = bf16_rne(r - fh - fm2);
    rh[(size_t)p*C4 + t] = hh;
    rm[(size_t)p*C4 + t] = hm;
    rl[(size_t)p*C4 + t] = hl;
    g1[t] = gg;
    g2[t] = e*r;
  }
  __syncthreads();
  // pwconv2 partials: group g covers o in [g*96, g*96+96)
  {
    float pa = 0.f, pb = 0.f;
    const float* w2p = ws + WS_W2T + (size_t)(g*96)*Cc + c;
    for (int oo=0; oo<96; oo++){
      float wv = w2p[(size_t)oo*Cc];
      pa = fmaf(wv, g1[g*96+oo], pa);
      pb = fmaf(wv, g2[g*96+oo], pb);
    }
    scp[g][c] = pa; btp[g][c] = pb;
  }
  __syncthreads();
  if (t < 96){
    float acc  = scp[0][t]+scp[1][t]+scp[2][t]+scp[3][t] + b2[t];
    float accb = btp[0][t]+btp[1][t]+btp[2][t]+btp[3][t] + b2[t];
    float gm = gamma[t];
    out[OFF_S  + t*Pp + p] = acc*gm  + signal[t*Pp + p];
    out[OFF_BT + t*Pp + p] = accb*gm + beta[t*Pp + p];
  }
}

// ---- K1 fallback (self-contained dwconv, writes f32 RATIO) ----
__global__ __launch_bounds__(384) void k1_fallback(
    const float* __restrict__ signal, const float* __restrict__ beta,
    const float* __restrict__ dw_w, const float* __restrict__ dw_b,
    const float* __restrict__ ln_w, const float* __restrict__ ln_b,
    const float* __restrict__ b1, const float* __restrict__ b2,
    const float* __restrict__ gamma, float* __restrict__ ws,
    float* __restrict__ out){
  int p = blockIdx.x, t = threadIdx.x;
  int h = p / Ww, w = p % Ww;
  int g = t / 96, c = t - g*96;
  __shared__ float scp[4][96], btp[4][96];
  __shared__ float sl[Cc], bl[Cc], g1[C4], g2[C4], red[2];
  float scpart = 0.f, btpart = 0.f;
  {
    const float* wk = dw_w + c*49;
    const float* sb = signal + c*Pp;
    const float* bb = beta   + c*Pp;
    #pragma unroll
    for (int kk=0; kk<2; kk++){
      int ky = g + kk*4;
      if (ky < 7){
        int y = h + ky - 3;
        if (y >= 0 && y < Hh){
          #pragma unroll
          for (int kx=0; kx<7; kx++){
            int x = w + kx - 3;
            if (x >= 0 && x < Ww){
              float wv = wk[ky*7+kx];
              scpart  += wv * sb[y*Ww + x];
              btpart  += wv * bb[y*Ww + x];
            }
          }
        }
      }
    }
  }
  scp[g][c] = scpart; btp[g][c] = btpart;
  __syncthreads();
  float sc = 0.f, btc = 0.f;
  if (t < 96){
    sc  = scp[0][t]+scp[1][t]+scp[2][t]+scp[3][t] + dw_b[t];
    btc = btp[0][t]+btp[1][t]+btp[2][t]+btp[3][t] + dw_b[t];
    scp[0][t] = sc;
  }
  __syncthreads();
  if (t < 64){
    float x = scp[0][t] + (t < 32 ? scp[0][64+t] : 0.f);
    #pragma unroll
    for (int off=32; off>0; off>>=1) x += __shfl_xor(x, off);
    if (t == 0) red[0] = x * (1.f/Cc);
  }
  __syncthreads();
  float u = red[0];
  if (t < 96){ float d = sc - u; scp[1][t] = d*d; }
  __syncthreads();
  if (t < 64){
    float x = scp[1][t] + (t < 32 ? scp[1][64+t] : 0.f);
    #pragma unroll
    for (int off=32; off>0; off>>=1) x += __shfl_xor(x, off);
    if (t == 0) red[1] = x * (1.f/Cc);
  }
  __syncthreads();
  float inv = 1.0f / sqrtf(red[1] + 1e-6f);
  if (t < 96){
    float scl = ln_w[t] * inv;
    ws[WS_SCALE + p*Cc + t] = scl;
    sl[t] = (sc - u)*inv*ln_w[t] + ln_b[t];
    bl[t] = btc*scl + (ln_b[t] - u*scl);
  }
  __syncthreads();
  {
    float a = b1[t], e = b1[t];
    const float* wp = ws + WS_W1T + t;
    for (int cc=0; cc<Cc; cc++){
      float wv = wp[cc*C4];
      a = fmaf(wv, sl[cc], a);
      e = fmaf(wv, bl[cc], e);
    }
    float x = a;
    float gg = 0.5f*x*(1.f + erff(x*0.70710678118654752f));
    float r = (fabsf(x) > 1e-6f) ? gg/x : 0.f;
    ws[WS_RATIO + p*C4 + t] = r;
    g1[t] = gg;
    g2[t] = e*r;
  }
  __syncthreads();
  {
    float pa = 0.f, pb = 0.f;
    const float* w2p = ws + WS_W2T + (size_t)(g*96)*Cc + c;
    for (int oo=0; oo<96; oo++){
      float wv = w2p[(size_t)oo*Cc];
      pa = fmaf(wv, g1[g*96+oo], pa);
      pb = fmaf(wv, g2[g*96+oo], pb);
    }
    scp[g][c] = pa; btp[g][c] = pb;
  }
  __syncthreads();
  if (t < 96){
    float acc  = scp[0][t]+scp[1][t]+scp[2][t]+scp[3][t] + b2[t];
    float accb = btp[0][t]+btp[1][t]+btp[2][t]+btp[3][t] + b2[t];
    float gm = gamma[t];
    out[OFF_S  + t*Pp + p] = acc*gm  + signal[t*Pp + p];
    out[OFF_BT + t*Pp + p] = accb*gm + beta[t*Pp + p];
  }
}

// ---- K2: depthwise 7x7 conv on phi, PRE-SCALED, 2-wide w reuse ----
// grid (96, 2, 8): c, w-pair/ss chunk, 5-row H strip. Adjacent windows share taps.
#define STRIP2 5
__global__ __launch_bounds__(256) void k2_phiconv(const float* __restrict__ phi,
    const float* __restrict__ dw_w, const float* __restrict__ wsc,
    float* __restrict__ out){
  int c = blockIdx.x;
  int task = blockIdx.y*256 + threadIdx.x;
  if (task >= 20*S4) return;          // 500 tasks
  int wp = task / S4, ss = task % S4;
  int w0 = wp*2;
  int s0 = blockIdx.z * STRIP2;
  float wk[49];
  #pragma unroll
  for (int i=0; i<49; i++) wk[i] = dw_w[c*49 + i];
  const float* base = phi + (size_t)c*Pp*Ss + ss*4;
  float* ob = out + OFF_PH + (size_t)c*Pp*Ss + ss*4;
  float4 z = make_float4(0.f,0.f,0.f,0.f);
  float4 a0=z,a1=z,a2=z,a3=z,a4=z,a5=z,a6=z;
  float4 b0=z,b1=z,b2=z,b3=z,b4=z,b5=z,b6=z;
  #pragma unroll
  for (int rr=0; rr<STRIP2+6; rr++){
    int r = s0 - 3 + rr;
    if (r >= 0 && r < Hh){
      #pragma unroll
      for (int xi=0; xi<8; xi++){
        int x = w0 - 3 + xi;
        if (x >= 0 && x < Ww){
          float4 in4 = *(const float4*)(base + ((size_t)r*Ww + x)*Ss);
          if (xi < 7){
            a0 = f4fma(a0, wk[42+xi], in4);
            a1 = f4fma(a1, wk[35+xi], in4);
            a2 = f4fma(a2, wk[28+xi], in4);
            a3 = f4fma(a3, wk[21+xi], in4);
            a4 = f4fma(a4, wk[14+xi], in4);
            a5 = f4fma(a5, wk[ 7+xi], in4);
            a6 = f4fma(a6, wk[ 0+xi], in4);
          }
          if (xi >= 1){
            int k1 = xi - 1;
            b0 = f4fma(b0, wk[42+k1], in4);
            b1 = f4fma(b1, wk[35+k1], in4);
            b2 = f4fma(b2, wk[28+k1], in4);
            b3 = f4fma(b3, wk[21+k1], in4);
            b4 = f4fma(b4, wk[14+k1], in4);
            b5 = f4fma(b5, wk[ 7+k1], in4);
            b6 = f4fma(b6, wk[ 0+k1], in4);
          }
        }
      }
    }
    int hrow = r - 3;
    if (hrow >= s0 && hrow < s0 + STRIP2 && hrow < Hh){
      float scv0 = wsc[WS_SCALE + (hrow*Ww + w0)*Cc + c];
      float4 o0v; o0v.x=a0.x*scv0; o0v.y=a0.y*scv0; o0v.z=a0.z*scv0; o0v.w=a0.w*scv0;
      *(float4*)(ob + ((size_t)hrow*Ww + w0)*Ss) = o0v;
      float scv1 = wsc[WS_SCALE + (hrow*Ww + w0+1)*Cc + c];
      float4 o1v; o1v.x=b0.x*scv1; o1v.y=b0.y*scv1; o1v.z=b0.z*scv1; o1v.w=b0.w*scv1;
      *(float4*)(ob + ((size_t)hrow*Ww + w0+1)*Ss) = o1v;
    }
    a0=a1; a1=a2; a2=a3; a3=a4; a4=a5; a5=a6; a6=z;
    b0=b1; b1=b2; b2=b3; b3=b4; b4=b5; b5=b6; b6=z;
  }
}

// ---- K3g: T[P0..][9216] = R x G^T, bf16 split-3 (6 MFMA passes), f32 out ----
// Epilogue: per-wave LDS transpose -> coalesced float4 stores.
__global__ __launch_bounds__(256) void k3g(float* __restrict__ wsm, int P0, int mtiles){
  const unsigned short* rH = (const unsigned short*)(wsm + WS_RH);
  const unsigned short* rM = (const unsigned short*)(wsm + WS_RM);
  const unsigned short* rL = (const unsigned short*)(wsm + WS_RL);
  const unsigned short* gH = (const unsigned short*)(wsm + WS_GH);
  const unsigned short* gM = (const unsigned short*)(wsm + WS_GM);
  const unsigned short* gL = (const unsigned short*)(wsm + WS_GL);
  float* tc = wsm + WS_T;

  int nblk = mtiles*72;
  int bid = blockIdx.x;
  int swz = (bid & 7)*(nblk>>3) + (bid >> 3);   // grid always %8==0
  int mt = swz % mtiles, nt = swz / mtiles;
  int m0 = mt*128, n0 = nt*128;
  int t = threadIdx.x, w = t >> 6, l = t & 63;

  __shared__ __align__(16) unsigned short lds[6*4096];
  unsigned short *AH = lds,        *AM = lds+4096,  *AL = lds+8192,
                 *BH = lds+12288,  *BM = lds+16384, *BL = lds+20480;

  f32x4_t acc[4][4];
  #pragma unroll
  for (int i=0;i<4;i++)
    #pragma unroll
    for (int j=0;j<4;j++) acc[i][j] = (f32x4_t){0.f,0.f,0.f,0.f};

  int wm = (w >> 1)*64, wn = (w & 1)*64;
  int srow = w*32 + (l>>2), sbyte = (l&3)*16;
  int pA0 = P0 + m0 + srow;      if (pA0 > Pp-1) pA0 = Pp-1;
  int pA1 = P0 + m0 + srow + 16; if (pA1 > Pp-1) pA1 = Pp-1;
  int nB0 = n0 + srow, nB1 = nB0 + 16;
  int kgb = (l>>4)*16;
  int lr  = l & 15;

  for (int ks=0; ks<12; ks++){
    int k0 = ks*32;
    size_t a0o = ((size_t)pA0*C4 + k0)*2 + sbyte;
    size_t a1o = ((size_t)pA1*C4 + k0)*2 + sbyte;
    size_t b0o = ((size_t)nB0*C4 + k0)*2 + sbyte;
    size_t b1o = ((size_t)nB1*C4 + k0)*2 + sbyte;
    gload16((const char*)rH + a0o, (char*)AH + w*2048);
    gload16((const char*)rH + a1o, (char*)AH + w*2048 + 1024);
    gload16((const char*)rM + a0o, (char*)AM + w*2048);
    gload16((const char*)rM + a1o, (char*)AM + w*2048 + 1024);
    gload16((const char*)rL + a0o, (char*)AL + w*2048);
    gload16((const char*)rL + a1o, (char*)AL + w*2048 + 1024);
    gload16((const char*)gH + b0o, (char*)BH + w*2048);
    gload16((const char*)gH + b1o, (char*)BH + w*2048 + 1024);
    gload16((const char*)gM + b0o, (char*)BM + w*2048);
    gload16((const char*)gM + b1o, (char*)BM + w*2048 + 1024);
    gload16((const char*)gL + b0o, (char*)BL + w*2048);
    gload16((const char*)gL + b1o, (char*)BL + w*2048 + 1024);
    asm volatile("s_waitcnt vmcnt(0)" ::: "memory");
    __syncthreads();

    bf16x8_t aH[4], aM[4], aL[4], bHf[4], bMf[4], bLf[4];
    #pragma unroll
    for (int f=0; f<4; f++){
      int ra = (wm + f*16 + lr)*64 + kgb;
      int rb = (wn + f*16 + lr)*64 + kgb;
      aH[f]  = *(const bf16x8_t*)((const char*)AH + ra);
      aM[f]  = *(const bf16x8_t*)((const char*)AM + ra);
      aL[f]  = *(const bf16x8_t*)((const char*)AL + ra);
      bHf[f] = *(const bf16x8_t*)((const char*)BH + rb);
      bMf[f] = *(const bf16x8_t*)((const char*)BM + rb);
      bLf[f] = *(const bf16x8_t*)((const char*)BL + rb);
    }
    #pragma unroll
    for (int i=0;i<4;i++)
      #pragma unroll
      for (int j=0;j<4;j++){
        acc[i][j] = __builtin_amdgcn_mfma_f32_16x16x32_bf16(aH[i], bHf[j], acc[i][j], 0,0,0);
        acc[i][j] = __builtin_amdgcn_mfma_f32_16x16x32_bf16(aH[i], bMf[j], acc[i][j], 0,0,0);
        acc[i][j] = __builtin_amdgcn_mfma_f32_16x16x32_bf16(aM[i], bHf[j], acc[i][j], 0,0,0);
        acc[i][j] = __builtin_amdgcn_mfma_f32_16x16x32_bf16(aH[i], bLf[j], acc[i][j], 0,0,0);
        acc[i][j] = __builtin_amdgcn_mfma_f32_16x16x32_bf16(aM[i], bMf[j], acc[i][j], 0,0,0);
        acc[i][j] = __builtin_amdgcn_mfma_f32_16x16x32_bf16(aL[i], bHf[j], acc[i][j], 0,0,0);
      }
    __syncthreads();
  }

  // Epilogue: per-wave transpose strips (16p x 64n) through private LDS slice,
  // then fully-coalesced float4 stores. No barriers needed (wave-private).
  float* scw = (float*)lds + w*1088;   // [16][68] per wave (4.3 KB), aliases staging
  #pragma unroll
  for (int fm=0; fm<4; fm++){
    #pragma unroll
    for (int fn=0; fn<4; fn++){
      #pragma unroll
      for (int r=0; r<4; r++)
        scw[((l>>4)*4 + r)*68 + fn*16 + lr] = acc[fm][fn][r];
    }
    #pragma unroll
    for (int it=0; it<4; it++){
      int row = (l>>4) + it*4;
      int p = P0 + m0 + wm + fm*16 + row;
      float4 v = *(float4*)&scw[row*68 + lr*4];
      if (p < Pp)
        *(float4*)&tc[(size_t)(p - P0)*Nn + n0 + wn + lr*4] = v;
    }
  }
}

// ---- K3b: ph_out = T * phc (+gamma,+residual), topk ----
// 1024 threads: 16 waves x 6 c-rows; lanes span 50 float2 s-chunks.
// T loads wave-uniform -> s_load (batch of 6); inner loop = pure fmaf chain.
#define PHP 100
__global__ __launch_bounds__(1024,2) void k3b_apply(const float* __restrict__ phi,
    const float* __restrict__ gamma, const float* __restrict__ wsm,
    float* __restrict__ out, int P0){
  int p = P0 + blockIdx.x, t = threadIdx.x;
  __shared__ float lp[9700];   // ph [96][100]; later absb overlay [100][97]
  const float* Tg = wsm + WS_T + (size_t)blockIdx.x*Nn;
  for (int q=t; q < Cc*S4; q += 1024){
    int cc = q/S4, sg = q%S4;
    *(float4*)&lp[cc*PHP + sg*4] =
      *(const float4*)(out + OFF_PH + (size_t)cc*Pp*Ss + (size_t)p*Ss + sg*4);
  }
  __syncthreads();
  int w = t >> 6, l = t & 63;
  int wu = __builtin_amdgcn_readfirstlane(w);       // wave-uniform SGPR
  const float* Tb = Tg + (size_t)wu*6*Cc;           // scalar base
  float2 acc[6];
  #pragma unroll
  for (int k=0;k<6;k++) acc[k] = make_float2(0.f,0.f);
  if (l < 50){
    for (int cb=0; cb<Cc; cb+=4){
      float2 pv0 = *(float2*)&lp[(cb+0)*PHP + l*2];
      float2 pv1 = *(float2*)&lp[(cb+1)*PHP + l*2];
      float2 pv2 = *(float2*)&lp[(cb+2)*PHP + l*2];
      float2 pv3 = *(float2*)&lp[(cb+3)*PHP + l*2];
      #pragma unroll
      for (int k=0;k<6;k++){
        float4 tv = *(const float4*)(Tb + k*Cc + cb);  // uniform -> s_load
        acc[k].x = fmaf(tv.x, pv0.x, acc[k].x);
        acc[k].y = fmaf(tv.x, pv0.y, acc[k].y);
        acc[k].x = fmaf(tv.y, pv1.x, acc[k].x);
        acc[k].y = fmaf(tv.y, pv1.y, acc[k].y);
        acc[k].x = fmaf(tv.z, pv2.x, acc[k].x);
        acc[k].y = fmaf(tv.z, pv2.y, acc[k].y);
        acc[k].x = fmaf(tv.w, pv3.x, acc[k].x);
        acc[k].y = fmaf(tv.w, pv3.y, acc[k].y);
      }
    }
    #pragma unroll
    for (int k=0;k<6;k++){
      int c = wu*6 + k;
      float gm = gamma[c];
      float2 pv = *(const float2*)(phi + (size_t)c*Pp*Ss + (size_t)p*Ss + l*2);
      float2 res;
      res.x = fmaf(acc[k].x, gm, pv.x); res.y = fmaf(acc[k].y, gm, pv.y);
      *(float2*)(out + OFF_PH + (size_t)c*Pp*Ss + (size_t)p*Ss + l*2) = res;
      acc[k].x = fabsf(acc[k].x); acc[k].y = fabsf(acc[k].y);
    }
  }
  __syncthreads();               // all ph reads done
  if (l < 50){
    #pragma unroll
    for (int k=0;k<6;k++){
      int c = wu*6 + k;
      lp[(l*2+0)*97 + c] = acc[k].x;
      lp[(l*2+1)*97 + c] = acc[k].y;
    }
  }
  __syncthreads();
  if (t < Cc){
    float v1=-1.f, v2=-1.f, v3=-1.f; int i1=0, i2=0, i3=0;
    for (int s=0; s<Ss; s++){
      float v = lp[s*97 + t];
      if (v > v1){ v3=v2;i3=i2; v2=v1;i2=i1; v1=v;i1=s; }
      else if (v > v2){ v3=v2;i3=i2; v2=v;i2=s; }
      else if (v > v3){ v3=v;i3=s; }
    }
    float* po = out + OFF_PI + (size_t)t*Pp*3 + (size_t)p*3;
    po[0] = (float)i1; po[1] = (float)i2; po[2] = (float)i3;
  }
}

// ---- Fallback fused K3 (ws too small): expects PRE-SCALED phc ----
__global__ __launch_bounds__(256) void k3_heavy(const float* __restrict__ phi,
     const float* __restrict__ w1, const float* __restrict__ gamma,
     const float* __restrict__ ws, float* __restrict__ out){
  int p = blockIdx.x, t = threadIdx.x;
  __shared__ float r_lds[C4];
  __shared__ float phc[Cc*Ss];
  __shared__ float Tm[Cc*Cc];
  __shared__ float pool[Cc*Ss];
  float* A1  = pool;
  float* W2s = pool + 32*Cc;
  r_lds[t] = ws[WS_RATIO + p*C4 + t];
  if (t < C4-256) r_lds[256+t] = ws[WS_RATIO + p*C4 + 256 + t];
  __syncthreads();
  for (int q=t; q < Cc*S4; q += 256){
    int cc = q/S4, s = q%S4;
    *(float4*)(phc + cc*Ss + s*4) =
      *(const float4*)(out + OFF_PH + (size_t)cc*Pp*Ss + (size_t)p*Ss + s*4);
  }
  int ti = t >> 4, tj = t & 15;
  float acc[6][6];
  #pragma unroll
  for (int k=0;k<6;k++)
    #pragma unroll
    for (int m=0;m<6;m++) acc[k][m] = 0.f;
  for (int ot=0; ot<C4; ot+=32){
    __syncthreads();
    for (int q=t; q < 32*Cc; q += 256){
      int oo = q/Cc, cc = q%Cc;
      A1[q]  = w1[(size_t)(ot+oo)*Cc + cc] * r_lds[ot+oo];
      W2s[q] = ws[WS_W2T + (ot+oo)*Cc + cc];
    }
    __syncthreads();
    #pragma unroll 4
    for (int oo=0; oo<32; oo++){
      float av[6], bv[6];
      #pragma unroll
      for (int m=0;m<6;m++) av[m] = A1[oo*Cc + tj*6 + m];
      #pragma unroll
      for (int k=0;k<6;k++) bv[k] = W2s[oo*Cc + ti*6 + k];
      #pragma unroll
      for (int k=0;k<6;k++)
        #pragma unroll
        for (int m=0;m<6;m++) acc[k][m] += bv[k]*av[m];
    }
  }
  __syncthreads();
  #pragma unroll
  for (int k=0;k<6;k++)
    #pragma unroll
    for (int m=0;m<6;m++) Tm[(ti*6+k)*Cc + tj*6 + m] = acc[k][m];
  __syncthreads();
  float* absb = pool;
  for (int q=t; q < 24*S4; q += 256){
    int cb = q/S4, s = q%S4;
    float4 z = make_float4(0.f,0.f,0.f,0.f);
    float4 o0=z, o1=z, o2=z, o3=z;
    const float* t0 = Tm + (cb*4+0)*Cc;
    const float* t1 = Tm + (cb*4+1)*Cc;
    const float* t2 = Tm + (cb*4+2)*Cc;
    const float* t3 = Tm + (cb*4+3)*Cc;
    for (int cc=0; cc<Cc; cc++){
      float4 ph4 = *(const float4*)(phc + cc*Ss + s*4);
      o0 = f4fma(o0, t0[cc], ph4);
      o1 = f4fma(o1, t1[cc], ph4);
      o2 = f4fma(o2, t2[cc], ph4);
      o3 = f4fma(o3, t3[cc], ph4);
    }
    float4 ov[4] = {o0,o1,o2,o3};
    #pragma unroll
    for (int k=0;k<4;k++){
      int c = cb*4 + k;
      float g = gamma[c];
      float4 pv = *(const float4*)(phi + (size_t)c*Pp*Ss + (size_t)p*Ss + s*4);
      float4 res;
      res.x = ov[k].x*g + pv.x; res.y = ov[k].y*g + pv.y;
      res.z = ov[k].z*g + pv.z; res.w = ov[k].w*g + pv.w;
      *(float4*)(out + OFF_PH + (size_t)c*Pp*Ss + (size_t)p*Ss + s*4) = res;
      absb[c*Ss + s*4 + 0] = fabsf(ov[k].x);
      absb[c*Ss + s*4 + 1] = fabsf(ov[k].y);
      absb[c*Ss + s*4 + 2] = fabsf(ov[k].z);
      absb[c*Ss + s*4 + 3] = fabsf(ov[k].w);
    }
  }
  __syncthreads();
  if (t < Cc){
    float v1=-1.f, v2=-1.f, v3=-1.f; int i1=0, i2=0, i3=0;
    for (int s=0; s<Ss; s++){
      float v = absb[t*Ss + s];
      if (v > v1){ v3=v2;i3=i2; v2=v1;i2=i1; v1=v;i1=s; }
      else if (v > v2){ v3=v2;i3=i2; v2=v;i2=s; }
      else if (v > v3){ v3=v;i3=s; }
    }
    float* po = out + OFF_PI + (size_t)t*Pp*3 + (size_t)p*3;
    po[0] = (float)i1; po[1] = (float)i2; po[2] = (float)i3;
  }
}

extern "C" void kernel_launch(void* const* d_in, const int* in_sizes, int n_in,
                              void* d_out, int out_size, void* d_ws, size_t ws_size,
                              hipStream_t stream){
  const float* signal = (const float*)d_in[0];
  const float* phi    = (const float*)d_in[1];
  const float* beta   = (const float*)d_in[2];
  const float* dw_w   = (const float*)d_in[3];
  const float* dw_b   = (const float*)d_in[4];
  const float* ln_w   = (const float*)d_in[5];
  const float* ln_b   = (const float*)d_in[6];
  const float* w1     = (const float*)d_in[7];
  const float* b1     = (const float*)d_in[8];
  const float* w2     = (const float*)d_in[9];
  const float* b2     = (const float*)d_in[10];
  const float* gamma  = (const float*)d_in[11];
  float* out = (float*)d_out;
  float* ws  = (float*)d_ws;

  size_t wsf = ws_size / 4;
  hipLaunchKernelGGL(k0_transpose, dim3(144), dim3(256), 0, stream, w1, w2, ws);

  if (wsf >= (size_t)WS_NEED_CHUNK){
    hipLaunchKernelGGL(k1a_dwconv, dim3(96,7), dim3(256), 0, stream,
                       signal, beta, dw_w, dw_b, ws);
    hipLaunchKernelGGL(k1_scalar, dim3(Pp), dim3(384), 0, stream,
                       signal, beta, ln_w, ln_b, b1, b2, gamma, ws, out);
  } else {
    hipLaunchKernelGGL(k1_fallback, dim3(Pp), dim3(384), 0, stream,
                       signal, beta, dw_w, dw_b, ln_w, ln_b, b1, b2, gamma, ws, out);
  }
  hipLaunchKernelGGL(k2_phiconv, dim3(96,2,8), dim3(256), 0, stream, phi, dw_w, ws, out);

  if (wsf >= (size_t)WS_NEED_FULL){
    hipLaunchKernelGGL(k0g3, dim3(Cc,8), dim3(256), 0, stream, w2, ws);
    hipLaunchKernelGGL(k3g, dim3(13*72), dim3(256), 0, stream, ws, 0, 13);
    hipLaunchKernelGGL(k3b_apply, dim3(Pp), dim3(1024), 0, stream, phi, gamma, ws, out, 0);
  } else if (wsf >= (size_t)WS_NEED_CHUNK){
    hipLaunchKernelGGL(k0g3, dim3(Cc,8), dim3(256), 0, stream, w2, ws);
    for (int P0 = 0; P0 < Pp; P0 += CHUNK){
      int cp = Pp - P0; if (cp > CHUNK) cp = CHUNK;
      int mtl = (cp + 127) / 128;
      hipLaunchKernelGGL(k3g, dim3(mtl*72), dim3(256), 0, stream, ws, P0, mtl);
      hipLaunchKernelGGL(k3b_apply, dim3(cp), dim3(1024), 0, stream, phi, gamma, ws, out, P0);
    }
  } else {
    hipLaunchKernelGGL(k3_heavy, dim3(Pp), dim3(256), 0, stream, phi, w1, gamma, ws, out);
  }
}

// Round 19
// 253.608 us; speedup vs baseline: 1.0594x; 1.0594x over previous
//
#include <hip/hip_runtime.h>
#include <math.h>

#define Cc 96
#define C4 384
#define Hh 40
#define Ww 40
#define Pp 1600
#define Ss 100
#define S4 25
#define Nn 9216   // 96*96

// d_out offsets (floats): s, ph, bt, pi
#define OFF_S  0
#define OFF_PH 153600
#define OFF_BT 15513600
#define OFF_PI 15667200

// ws offsets (floats)
#define WS_W1T   0
#define WS_W2T   36864
#define WS_RATIO 73728
#define WS_SC    WS_RATIO            // [c][p] dwconv(signal)+b, MFMA path only
#define WS_BC    (WS_RATIO + 153600) // [c][p] dwconv(beta)+b
#define WS_SCALE 688128
#define WS_RH    841728     // ushort[1600][384] -> 307200 float slots each
#define WS_RM    1148928
#define WS_RL    1456128
#define WS_GH    1763328    // ushort[9216][384] -> 1769472 float slots each
#define WS_GM    3532800
#define WS_GL    5302272
#define WS_T     7071744    // f32 T buffer (full or chunk)
#define CHUNK    640
#define WS_NEED_CHUNK (WS_T + CHUNK*Nn)   // 12969984 floats (51.9 MB)
#define WS_NEED_FULL  (WS_T + Pp*Nn)      // 21817344 floats (87.3 MB)

typedef __attribute__((ext_vector_type(8))) short bf16x8_t;
typedef __attribute__((ext_vector_type(4))) float f32x4_t;

__device__ inline float4 f4fma(float4 a, float w, float4 b){
  a.x += w*b.x; a.y += w*b.y; a.z += w*b.z; a.w += w*b.w; return a;
}
__device__ inline unsigned short bf16_rne(float x){
  unsigned int u = __float_as_uint(x);
  return (unsigned short)((u + 0x7fffu + ((u>>16)&1u)) >> 16);
}
__device__ inline float bf16_to_f(unsigned short h){
  return __uint_as_float(((unsigned int)h)<<16);
}
__device__ inline void gload16(const void* g, void* l){
  __builtin_amdgcn_global_load_lds(
    (const __attribute__((address_space(1))) void*)g,
    (__attribute__((address_space(3))) void*)l, 16, 0, 0);
}

// ---- K0: transpose w1 -> w1T[c][o], w2 -> w2T[o][c] ----
__global__ __launch_bounds__(256) void k0_transpose(const float* __restrict__ w1,
    const float* __restrict__ w2, float* __restrict__ ws){
  int idx = blockIdx.x*256 + threadIdx.x;
  if (idx < C4*Cc){
    int o = idx/Cc, c = idx%Cc;
    ws[WS_W1T + c*C4 + o] = w1[idx];
    int c2 = idx/C4, o2 = idx%C4;
    ws[WS_W2T + o2*Cc + c2] = w2[idx];
  }
}

// ---- K0g3: G[i*96+j][o] = w2[i][o]*w1T[j][o], 3 bf16 levels ----
__global__ __launch_bounds__(256) void k0g3(const float* __restrict__ w2,
    float* __restrict__ wsm){
  int i = blockIdx.x;
  int base = blockIdx.y * (Cc*C4/8);
  unsigned short* gh = (unsigned short*)(wsm + WS_GH);
  unsigned short* gm = (unsigned short*)(wsm + WS_GM);
  unsigned short* gl = (unsigned short*)(wsm + WS_GL);
  for (int k = threadIdx.x; k < Cc*C4/8; k += 256){
    int idx = base + k;
    int j = idx / C4, o = idx % C4;
    float g = w2[i*C4 + o] * wsm[WS_W1T + j*C4 + o];
    unsigned short h = bf16_rne(g);           float fh = bf16_to_f(h);
    unsigned short m = bf16_rne(g - fh);      float fm2 = bf16_to_f(m);
    unsigned short lo = bf16_rne(g - fh - fm2);
    size_t off = ((size_t)i*Cc + j)*C4 + o;
    gh[off] = h; gm[off] = m; gl[off] = lo;
  }
}

// ---- K1a: dwconv7x7 of signal & beta, coalesced (lanes = pixels) ----
__global__ __launch_bounds__(256) void k1a_dwconv(const float* __restrict__ signal,
    const float* __restrict__ beta, const float* __restrict__ dw_w,
    const float* __restrict__ dw_b, float* __restrict__ ws){
  int c = blockIdx.x;
  int pp = blockIdx.y*256 + threadIdx.x;
  if (pp >= Pp) return;
  int h = pp / Ww, w = pp % Ww;
  float wk[49];
  #pragma unroll
  for (int i=0; i<49; i++) wk[i] = dw_w[c*49 + i];   // wave-uniform
  const float* sb = signal + (size_t)c*Pp;
  const float* bb = beta   + (size_t)c*Pp;
  float sc = 0.f, btc = 0.f;
  #pragma unroll
  for (int ky=0; ky<7; ky++){
    int y = h + ky - 3;
    if (y >= 0 && y < Hh){
      #pragma unroll
      for (int kx=0; kx<7; kx++){
        int x = w + kx - 3;
        if (x >= 0 && x < Ww){
          float wv = wk[ky*7+kx];
          sc  = fmaf(wv, sb[y*Ww + x], sc);
          btc = fmaf(wv, bb[y*Ww + x], btc);
        }
      }
    }
  }
  float b = dw_b[c];
  ws[WS_SC + (size_t)c*Pp + pp] = sc + b;
  ws[WS_BC + (size_t)c*Pp + pp] = btc + b;
}

// ---- K1: scalar path (s, bt), 384 threads; dwconv read from WS_SC/WS_BC ----
__global__ __launch_bounds__(384) void k1_scalar(
    const float* __restrict__ signal, const float* __restrict__ beta,
    const float* __restrict__ ln_w, const float* __restrict__ ln_b,
    const float* __restrict__ b1, const float* __restrict__ b2,
    const float* __restrict__ gamma, float* __restrict__ ws,
    float* __restrict__ out){
  int p = blockIdx.x, t = threadIdx.x;
  int g = t / 96, c = t - g*96;
  __shared__ float scp[4][96], btp[4][96];
  __shared__ float sl[Cc], bl[Cc], g1[C4], g2[C4], red[2];

  float sc = 0.f, btc = 0.f;
  if (t < 96){
    sc  = ws[WS_SC + (size_t)t*Pp + p];
    btc = ws[WS_BC + (size_t)t*Pp + p];
    scp[0][t] = sc;
  }
  __syncthreads();
  if (t < 64){
    float x = scp[0][t] + (t < 32 ? scp[0][64+t] : 0.f);
    #pragma unroll
    for (int off=32; off>0; off>>=1) x += __shfl_xor(x, off);
    if (t == 0) red[0] = x * (1.f/Cc);
  }
  __syncthreads();
  float u = red[0];
  if (t < 96){ float d = sc - u; scp[1][t] = d*d; }
  __syncthreads();
  if (t < 64){
    float x = scp[1][t] + (t < 32 ? scp[1][64+t] : 0.f);
    #pragma unroll
    for (int off=32; off>0; off>>=1) x += __shfl_xor(x, off);
    if (t == 0) red[1] = x * (1.f/Cc);
  }
  __syncthreads();
  float inv = 1.0f / sqrtf(red[1] + 1e-6f);
  if (t < 96){
    float scl = ln_w[t] * inv;
    ws[WS_SCALE + p*Cc + t] = scl;
    sl[t] = (sc - u)*inv*ln_w[t] + ln_b[t];
    bl[t] = btc*scl + (ln_b[t] - u*scl);
  }
  __syncthreads();
  // pwconv1: thread t = o (coalesced w1T column reads)
  {
    float a = b1[t], e = b1[t];
    const float* wp = ws + WS_W1T + t;
    for (int cc=0; cc<Cc; cc++){
      float wv = wp[cc*C4];
      a = fmaf(wv, sl[cc], a);
      e = fmaf(wv, bl[cc], e);
    }
    float x = a;
    float gg = 0.5f*x*(1.f + erff(x*0.70710678118654752f));
    float r = (fabsf(x) > 1e-6f) ? gg/x : 0.f;
    unsigned short* rh = (unsigned short*)(ws + WS_RH);
    unsigned short* rm = (unsigned short*)(ws + WS_RM);
    unsigned short* rl = (unsigned short*)(ws + WS_RL);
    unsigned short hh = bf16_rne(r);          float fh = bf16_to_f(hh);
    unsigned short hm = bf16_rne(r - fh);     float fm2 = bf16_to_f(hm);
    unsigned short hl = bf16_rne(r - fh - fm2);
    rh[(size_t)p*C4 + t] = hh;
    rm[(size_t)p*C4 + t] = hm;
    rl[(size_t)p*C4 + t] = hl;
    g1[t] = gg;
    g2[t] = e*r;
  }
  __syncthreads();
  // pwconv2 partials: group g covers o in [g*96, g*96+96)
  {
    float pa = 0.f, pb = 0.f;
    const float* w2p = ws + WS_W2T + (size_t)(g*96)*Cc + c;
    for (int oo=0; oo<96; oo++){
      float wv = w2p[(size_t)oo*Cc];
      pa = fmaf(wv, g1[g*96+oo], pa);
      pb = fmaf(wv, g2[g*96+oo], pb);
    }
    scp[g][c] = pa; btp[g][c] = pb;
  }
  __syncthreads();
  if (t < 96){
    float acc  = scp[0][t]+scp[1][t]+scp[2][t]+scp[3][t] + b2[t];
    float accb = btp[0][t]+btp[1][t]+btp[2][t]+btp[3][t] + b2[t];
    float gm = gamma[t];
    out[OFF_S  + t*Pp + p] = acc*gm  + signal[t*Pp + p];
    out[OFF_BT + t*Pp + p] = accb*gm + beta[t*Pp + p];
  }
}

// ---- K1 fallback (self-contained dwconv, writes f32 RATIO) ----
__global__ __launch_bounds__(384) void k1_fallback(
    const float* __restrict__ signal, const float* __restrict__ beta,
    const float* __restrict__ dw_w, const float* __restrict__ dw_b,
    const float* __restrict__ ln_w, const float* __restrict__ ln_b,
    const float* __restrict__ b1, const float* __restrict__ b2,
    const float* __restrict__ gamma, float* __restrict__ ws,
    float* __restrict__ out){
  int p = blockIdx.x, t = threadIdx.x;
  int h = p / Ww, w = p % Ww;
  int g = t / 96, c = t - g*96;
  __shared__ float scp[4][96], btp[4][96];
  __shared__ float sl[Cc], bl[Cc], g1[C4], g2[C4], red[2];
  float scpart = 0.f, btpart = 0.f;
  {
    const float* wk = dw_w + c*49;
    const float* sb = signal + c*Pp;
    const float* bb = beta   + c*Pp;
    #pragma unroll
    for (int kk=0; kk<2; kk++){
      int ky = g + kk*4;
      if (ky < 7){
        int y = h + ky - 3;
        if (y >= 0 && y < Hh){
          #pragma unroll
          for (int kx=0; kx<7; kx++){
            int x = w + kx - 3;
            if (x >= 0 && x < Ww){
              float wv = wk[ky*7+kx];
              scpart  += wv * sb[y*Ww + x];
              btpart  += wv * bb[y*Ww + x];
            }
          }
        }
      }
    }
  }
  scp[g][c] = scpart; btp[g][c] = btpart;
  __syncthreads();
  float sc = 0.f, btc = 0.f;
  if (t < 96){
    sc  = scp[0][t]+scp[1][t]+scp[2][t]+scp[3][t] + dw_b[t];
    btc = btp[0][t]+btp[1][t]+btp[2][t]+btp[3][t] + dw_b[t];
    scp[0][t] = sc;
  }
  __syncthreads();
  if (t < 64){
    float x = scp[0][t] + (t < 32 ? scp[0][64+t] : 0.f);
    #pragma unroll
    for (int off=32; off>0; off>>=1) x += __shfl_xor(x, off);
    if (t == 0) red[0] = x * (1.f/Cc);
  }
  __syncthreads();
  float u = red[0];
  if (t < 96){ float d = sc - u; scp[1][t] = d*d; }
  __syncthreads();
  if (t < 64){
    float x = scp[1][t] + (t < 32 ? scp[1][64+t] : 0.f);
    #pragma unroll
    for (int off=32; off>0; off>>=1) x += __shfl_xor(x, off);
    if (t == 0) red[1] = x * (1.f/Cc);
  }
  __syncthreads();
  float inv = 1.0f / sqrtf(red[1] + 1e-6f);
  if (t < 96){
    float scl = ln_w[t] * inv;
    ws[WS_SCALE + p*Cc + t] = scl;
    sl[t] = (sc - u)*inv*ln_w[t] + ln_b[t];
    bl[t] = btc*scl + (ln_b[t] - u*scl);
  }
  __syncthreads();
  {
    float a = b1[t], e = b1[t];
    const float* wp = ws + WS_W1T + t;
    for (int cc=0; cc<Cc; cc++){
      float wv = wp[cc*C4];
      a = fmaf(wv, sl[cc], a);
      e = fmaf(wv, bl[cc], e);
    }
    float x = a;
    float gg = 0.5f*x*(1.f + erff(x*0.70710678118654752f));
    float r = (fabsf(x) > 1e-6f) ? gg/x : 0.f;
    ws[WS_RATIO + p*C4 + t] = r;
    g1[t] = gg;
    g2[t] = e*r;
  }
  __syncthreads();
  {
    float pa = 0.f, pb = 0.f;
    const float* w2p = ws + WS_W2T + (size_t)(g*96)*Cc + c;
    for (int oo=0; oo<96; oo++){
      float wv = w2p[(size_t)oo*Cc];
      pa = fmaf(wv, g1[g*96+oo], pa);
      pb = fmaf(wv, g2[g*96+oo], pb);
    }
    scp[g][c] = pa; btp[g][c] = pb;
  }
  __syncthreads();
  if (t < 96){
    float acc  = scp[0][t]+scp[1][t]+scp[2][t]+scp[3][t] + b2[t];
    float accb = btp[0][t]+btp[1][t]+btp[2][t]+btp[3][t] + b2[t];
    float gm = gamma[t];
    out[OFF_S  + t*Pp + p] = acc*gm  + signal[t*Pp + p];
    out[OFF_BT + t*Pp + p] = accb*gm + beta[t*Pp + p];
  }
}

// ---- K2: depthwise 7x7 conv on phi, PRE-SCALED, H-strip parallel ----
#define STRIP 10
__global__ __launch_bounds__(256) void k2_phiconv(const float* __restrict__ phi,
    const float* __restrict__ dw_w, const float* __restrict__ wsc,
    float* __restrict__ out){
  int c = blockIdx.x;
  int task = blockIdx.y*256 + threadIdx.x;
  if (task >= Ww*S4) return;
  int w = task / S4, ss = task % S4;
  int s0 = blockIdx.z * STRIP;
  float wk[49];
  #pragma unroll
  for (int i=0; i<49; i++) wk[i] = dw_w[c*49 + i];
  const float* base = phi + (size_t)c*Pp*Ss + ss*4;
  float* ob = out + OFF_PH + (size_t)c*Pp*Ss + (size_t)w*Ss + ss*4;
  float4 z = make_float4(0.f,0.f,0.f,0.f);
  float4 a0=z,a1=z,a2=z,a3=z,a4=z,a5=z,a6=z;
  #pragma unroll
  for (int rr=0; rr<STRIP+6; rr++){
    int r = s0 - 3 + rr;
    if (r >= 0 && r < Hh){
      #pragma unroll
      for (int kx=0; kx<7; kx++){
        int x = w + kx - 3;
        if (x >= 0 && x < Ww){
          float4 in4 = *(const float4*)(base + ((size_t)r*Ww + x)*Ss);
          a0 = f4fma(a0, wk[42+kx], in4);
          a1 = f4fma(a1, wk[35+kx], in4);
          a2 = f4fma(a2, wk[28+kx], in4);
          a3 = f4fma(a3, wk[21+kx], in4);
          a4 = f4fma(a4, wk[14+kx], in4);
          a5 = f4fma(a5, wk[ 7+kx], in4);
          a6 = f4fma(a6, wk[ 0+kx], in4);
        }
      }
    }
    int hrow = r - 3;
    if (hrow >= s0 && hrow < s0 + STRIP && hrow < Hh){
      float scv = wsc[WS_SCALE + (hrow*Ww + w)*Cc + c];
      float4 o; o.x=a0.x*scv; o.y=a0.y*scv; o.z=a0.z*scv; o.w=a0.w*scv;
      *(float4*)(ob + (size_t)hrow*Ww*Ss) = o;
    }
    a0=a1; a1=a2; a2=a3; a3=a4; a4=a5; a5=a6; a6=z;
  }
}

// ---- K3g: T[P0..][9216] = R x G^T, bf16 split-3 (6 MFMA passes), f32 out ----
// Epilogue: per-wave LDS transpose -> coalesced float4 stores.
__global__ __launch_bounds__(256) void k3g(float* __restrict__ wsm, int P0, int mtiles){
  const unsigned short* rH = (const unsigned short*)(wsm + WS_RH);
  const unsigned short* rM = (const unsigned short*)(wsm + WS_RM);
  const unsigned short* rL = (const unsigned short*)(wsm + WS_RL);
  const unsigned short* gH = (const unsigned short*)(wsm + WS_GH);
  const unsigned short* gM = (const unsigned short*)(wsm + WS_GM);
  const unsigned short* gL = (const unsigned short*)(wsm + WS_GL);
  float* tc = wsm + WS_T;

  int nblk = mtiles*72;
  int bid = blockIdx.x;
  int swz = (bid & 7)*(nblk>>3) + (bid >> 3);   // grid always %8==0
  int mt = swz % mtiles, nt = swz / mtiles;
  int m0 = mt*128, n0 = nt*128;
  int t = threadIdx.x, w = t >> 6, l = t & 63;

  __shared__ __align__(16) unsigned short lds[6*4096];
  unsigned short *AH = lds,        *AM = lds+4096,  *AL = lds+8192,
                 *BH = lds+12288,  *BM = lds+16384, *BL = lds+20480;

  f32x4_t acc[4][4];
  #pragma unroll
  for (int i=0;i<4;i++)
    #pragma unroll
    for (int j=0;j<4;j++) acc[i][j] = (f32x4_t){0.f,0.f,0.f,0.f};

  int wm = (w >> 1)*64, wn = (w & 1)*64;
  int srow = w*32 + (l>>2), sbyte = (l&3)*16;
  int pA0 = P0 + m0 + srow;      if (pA0 > Pp-1) pA0 = Pp-1;
  int pA1 = P0 + m0 + srow + 16; if (pA1 > Pp-1) pA1 = Pp-1;
  int nB0 = n0 + srow, nB1 = nB0 + 16;
  int kgb = (l>>4)*16;
  int lr  = l & 15;

  for (int ks=0; ks<12; ks++){
    int k0 = ks*32;
    size_t a0o = ((size_t)pA0*C4 + k0)*2 + sbyte;
    size_t a1o = ((size_t)pA1*C4 + k0)*2 + sbyte;
    size_t b0o = ((size_t)nB0*C4 + k0)*2 + sbyte;
    size_t b1o = ((size_t)nB1*C4 + k0)*2 + sbyte;
    gload16((const char*)rH + a0o, (char*)AH + w*2048);
    gload16((const char*)rH + a1o, (char*)AH + w*2048 + 1024);
    gload16((const char*)rM + a0o, (char*)AM + w*2048);
    gload16((const char*)rM + a1o, (char*)AM + w*2048 + 1024);
    gload16((const char*)rL + a0o, (char*)AL + w*2048);
    gload16((const char*)rL + a1o, (char*)AL + w*2048 + 1024);
    gload16((const char*)gH + b0o, (char*)BH + w*2048);
    gload16((const char*)gH + b1o, (char*)BH + w*2048 + 1024);
    gload16((const char*)gM + b0o, (char*)BM + w*2048);
    gload16((const char*)gM + b1o, (char*)BM + w*2048 + 1024);
    gload16((const char*)gL + b0o, (char*)BL + w*2048);
    gload16((const char*)gL + b1o, (char*)BL + w*2048 + 1024);
    asm volatile("s_waitcnt vmcnt(0)" ::: "memory");
    __syncthreads();

    bf16x8_t aH[4], aM[4], aL[4], bHf[4], bMf[4], bLf[4];
    #pragma unroll
    for (int f=0; f<4; f++){
      int ra = (wm + f*16 + lr)*64 + kgb;
      int rb = (wn + f*16 + lr)*64 + kgb;
      aH[f]  = *(const bf16x8_t*)((const char*)AH + ra);
      aM[f]  = *(const bf16x8_t*)((const char*)AM + ra);
      aL[f]  = *(const bf16x8_t*)((const char*)AL + ra);
      bHf[f] = *(const bf16x8_t*)((const char*)BH + rb);
      bMf[f] = *(const bf16x8_t*)((const char*)BM + rb);
      bLf[f] = *(const bf16x8_t*)((const char*)BL + rb);
    }
    #pragma unroll
    for (int i=0;i<4;i++)
      #pragma unroll
      for (int j=0;j<4;j++){
        acc[i][j] = __builtin_amdgcn_mfma_f32_16x16x32_bf16(aH[i], bHf[j], acc[i][j], 0,0,0);
        acc[i][j] = __builtin_amdgcn_mfma_f32_16x16x32_bf16(aH[i], bMf[j], acc[i][j], 0,0,0);
        acc[i][j] = __builtin_amdgcn_mfma_f32_16x16x32_bf16(aM[i], bHf[j], acc[i][j], 0,0,0);
        acc[i][j] = __builtin_amdgcn_mfma_f32_16x16x32_bf16(aH[i], bLf[j], acc[i][j], 0,0,0);
        acc[i][j] = __builtin_amdgcn_mfma_f32_16x16x32_bf16(aM[i], bMf[j], acc[i][j], 0,0,0);
        acc[i][j] = __builtin_amdgcn_mfma_f32_16x16x32_bf16(aL[i], bHf[j], acc[i][j], 0,0,0);
      }
    __syncthreads();
  }

  // Epilogue: per-wave transpose strips (16p x 64n) through private LDS slice,
  // then fully-coalesced float4 stores. No barriers needed (wave-private).
  float* scw = (float*)lds + w*1088;   // [16][68] per wave (4.3 KB), aliases staging
  #pragma unroll
  for (int fm=0; fm<4; fm++){
    #pragma unroll
    for (int fn=0; fn<4; fn++){
      #pragma unroll
      for (int r=0; r<4; r++)
        scw[((l>>4)*4 + r)*68 + fn*16 + lr] = acc[fm][fn][r];
    }
    #pragma unroll
    for (int it=0; it<4; it++){
      int row = (l>>4) + it*4;
      int p = P0 + m0 + wm + fm*16 + row;
      float4 v = *(float4*)&scw[row*68 + lr*4];
      if (p < Pp)
        *(float4*)&tc[(size_t)(p - P0)*Nn + n0 + wn + lr*4] = v;
    }
  }
}

// ---- K3b: ph_out = T * phc (+gamma,+residual), topk ----
// 512 threads: 8 waves x 12 c-rows; lanes span 50 float2 s-chunks.
// T loads wave-uniform -> s_load; fmaf chain. Topk: 4 lanes per channel.
#define PHP 100
__global__ __launch_bounds__(512,6) void k3b_apply(const float* __restrict__ phi,
    const float* __restrict__ gamma, const float* __restrict__ wsm,
    float* __restrict__ out, int P0){
  int p = P0 + blockIdx.x, t = threadIdx.x;
  __shared__ float lp[9700];   // ph [96][100]; later absb overlay [100][97]
  const float* Tg = wsm + WS_T + (size_t)blockIdx.x*Nn;
  for (int q=t; q < Cc*S4; q += 512){
    int cc = q/S4, sg = q%S4;
    *(float4*)&lp[cc*PHP + sg*4] =
      *(const float4*)(out + OFF_PH + (size_t)cc*Pp*Ss + (size_t)p*Ss + sg*4);
  }
  __syncthreads();
  int w = t >> 6, l = t & 63;
  int wu = __builtin_amdgcn_readfirstlane(w);       // wave-uniform SGPR
  const float* Tb = Tg + (size_t)wu*12*Cc;          // scalar base
  float2 acc[12];
  #pragma unroll
  for (int k=0;k<12;k++) acc[k] = make_float2(0.f,0.f);
  if (l < 50){
    for (int cb=0; cb<Cc; cb+=4){
      float2 pv0 = *(float2*)&lp[(cb+0)*PHP + l*2];
      float2 pv1 = *(float2*)&lp[(cb+1)*PHP + l*2];
      float2 pv2 = *(float2*)&lp[(cb+2)*PHP + l*2];
      float2 pv3 = *(float2*)&lp[(cb+3)*PHP + l*2];
      #pragma unroll
      for (int k=0;k<12;k++){
        float4 tv = *(const float4*)(Tb + k*Cc + cb);  // uniform -> s_load
        acc[k].x = fmaf(tv.x, pv0.x, acc[k].x);
        acc[k].y = fmaf(tv.x, pv0.y, acc[k].y);
        acc[k].x = fmaf(tv.y, pv1.x, acc[k].x);
        acc[k].y = fmaf(tv.y, pv1.y, acc[k].y);
        acc[k].x = fmaf(tv.z, pv2.x, acc[k].x);
        acc[k].y = fmaf(tv.z, pv2.y, acc[k].y);
        acc[k].x = fmaf(tv.w, pv3.x, acc[k].x);
        acc[k].y = fmaf(tv.w, pv3.y, acc[k].y);
      }
    }
    #pragma unroll
    for (int k=0;k<12;k++){
      int c = wu*12 + k;
      float gm = gamma[c];
      float2 pv = *(const float2*)(phi + (size_t)c*Pp*Ss + (size_t)p*Ss + l*2);
      float2 res;
      res.x = fmaf(acc[k].x, gm, pv.x); res.y = fmaf(acc[k].y, gm, pv.y);
      *(float2*)(out + OFF_PH + (size_t)c*Pp*Ss + (size_t)p*Ss + l*2) = res;
      acc[k].x = fabsf(acc[k].x); acc[k].y = fabsf(acc[k].y);
    }
  }
  __syncthreads();               // all ph reads done
  if (l < 50){
    #pragma unroll
    for (int k=0;k<12;k++){
      int c = wu*12 + k;
      lp[(l*2+0)*97 + c] = acc[k].x;
      lp[(l*2+1)*97 + c] = acc[k].y;
    }
  }
  __syncthreads();
  // topk: 4 lanes per channel (threads 0..383); lane q scans s in [q*25,(q+1)*25)
  if (t < 384){
    int c = t >> 2, q = t & 3;
    int sbase = q*25;
    float v1=-1.f, v2=-1.f, v3=-1.f; int i1=0, i2=0, i3=0;
    for (int s2=0; s2<25; s2++){
      int s = sbase + s2;
      float v = lp[s*97 + c];
      if (v > v1){ v3=v2;i3=i2; v2=v1;i2=i1; v1=v;i1=s; }
      else if (v > v2){ v3=v2;i3=i2; v2=v;i2=s; }
      else if (v > v3){ v3=v;i3=s; }
    }
    // merge 4 lanes' top-3 in q order (strict > keeps lower-index on ties)
    int g4 = t & ~3;
    float m1=-1.f, m2=-1.f, m3=-1.f; int j1=0, j2=0, j3=0;
    #pragma unroll
    for (int src=0; src<4; src++){
      float cv1 = __shfl(v1, g4+src), cv2 = __shfl(v2, g4+src), cv3 = __shfl(v3, g4+src);
      int   ci1 = __shfl(i1, g4+src), ci2 = __shfl(i2, g4+src), ci3 = __shfl(i3, g4+src);
      if (cv1 > m1){ m3=m2;j3=j2; m2=m1;j2=j1; m1=cv1;j1=ci1; }
      else if (cv1 > m2){ m3=m2;j3=j2; m2=cv1;j2=ci1; }
      else if (cv1 > m3){ m3=cv1;j3=ci1; }
      if (cv2 > m1){ m3=m2;j3=j2; m2=m1;j2=j1; m1=cv2;j1=ci2; }
      else if (cv2 > m2){ m3=m2;j3=j2; m2=cv2;j2=ci2; }
      else if (cv2 > m3){ m3=cv2;j3=ci2; }
      if (cv3 > m1){ m3=m2;j3=j2; m2=m1;j2=j1; m1=cv3;j1=ci3; }
      else if (cv3 > m2){ m3=m2;j3=j2; m2=cv3;j2=ci3; }
      else if (cv3 > m3){ m3=cv3;j3=ci3; }
    }
    if (q == 0){
      float* po = out + OFF_PI + (size_t)c*Pp*3 + (size_t)p*3;
      po[0] = (float)j1; po[1] = (float)j2; po[2] = (float)j3;
    }
  }
}

// ---- Fallback fused K3 (ws too small): expects PRE-SCALED phc ----
__global__ __launch_bounds__(256) void k3_heavy(const float* __restrict__ phi,
     const float* __restrict__ w1, const float* __restrict__ gamma,
     const float* __restrict__ ws, float* __restrict__ out){
  int p = blockIdx.x, t = threadIdx.x;
  __shared__ float r_lds[C4];
  __shared__ float phc[Cc*Ss];
  __shared__ float Tm[Cc*Cc];
  __shared__ float pool[Cc*Ss];
  float* A1  = pool;
  float* W2s = pool + 32*Cc;
  r_lds[t] = ws[WS_RATIO + p*C4 + t];
  if (t < C4-256) r_lds[256+t] = ws[WS_RATIO + p*C4 + 256 + t];
  __syncthreads();
  for (int q=t; q < Cc*S4; q += 256){
    int cc = q/S4, s = q%S4;
    *(float4*)(phc + cc*Ss + s*4) =
      *(const float4*)(out + OFF_PH + (size_t)cc*Pp*Ss + (size_t)p*Ss + s*4);
  }
  int ti = t >> 4, tj = t & 15;
  float acc[6][6];
  #pragma unroll
  for (int k=0;k<6;k++)
    #pragma unroll
    for (int m=0;m<6;m++) acc[k][m] = 0.f;
  for (int ot=0; ot<C4; ot+=32){
    __syncthreads();
    for (int q=t; q < 32*Cc; q += 256){
      int oo = q/Cc, cc = q%Cc;
      A1[q]  = w1[(size_t)(ot+oo)*Cc + cc] * r_lds[ot+oo];
      W2s[q] = ws[WS_W2T + (ot+oo)*Cc + cc];
    }
    __syncthreads();
    #pragma unroll 4
    for (int oo=0; oo<32; oo++){
      float av[6], bv[6];
      #pragma unroll
      for (int m=0;m<6;m++) av[m] = A1[oo*Cc + tj*6 + m];
      #pragma unroll
      for (int k=0;k<6;k++) bv[k] = W2s[oo*Cc + ti*6 + k];
      #pragma unroll
      for (int k=0;k<6;k++)
        #pragma unroll
        for (int m=0;m<6;m++) acc[k][m] += bv[k]*av[m];
    }
  }
  __syncthreads();
  #pragma unroll
  for (int k=0;k<6;k++)
    #pragma unroll
    for (int m=0;m<6;m++) Tm[(ti*6+k)*Cc + tj*6 + m] = acc[k][m];
  __syncthreads();
  float* absb = pool;
  for (int q=t; q < 24*S4; q += 256){
    int cb = q/S4, s = q%S4;
    float4 z = make_float4(0.f,0.f,0.f,0.f);
    float4 o0=z, o1=z, o2=z, o3=z;
    const float* t0 = Tm + (cb*4+0)*Cc;
    const float* t1 = Tm + (cb*4+1)*Cc;
    const float* t2 = Tm + (cb*4+2)*Cc;
    const float* t3 = Tm + (cb*4+3)*Cc;
    for (int cc=0; cc<Cc; cc++){
      float4 ph4 = *(const float4*)(phc + cc*Ss + s*4);
      o0 = f4fma(o0, t0[cc], ph4);
      o1 = f4fma(o1, t1[cc], ph4);
      o2 = f4fma(o2, t2[cc], ph4);
      o3 = f4fma(o3, t3[cc], ph4);
    }
    float4 ov[4] = {o0,o1,o2,o3};
    #pragma unroll
    for (int k=0;k<4;k++){
      int c = cb*4 + k;
      float g = gamma[c];
      float4 pv = *(const float4*)(phi + (size_t)c*Pp*Ss + (size_t)p*Ss + s*4);
      float4 res;
      res.x = ov[k].x*g + pv.x; res.y = ov[k].y*g + pv.y;
      res.z = ov[k].z*g + pv.z; res.w = ov[k].w*g + pv.w;
      *(float4*)(out + OFF_PH + (size_t)c*Pp*Ss + (size_t)p*Ss + s*4) = res;
      absb[c*Ss + s*4 + 0] = fabsf(ov[k].x);
      absb[c*Ss + s*4 + 1] = fabsf(ov[k].y);
      absb[c*Ss + s*4 + 2] = fabsf(ov[k].z);
      absb[c*Ss + s*4 + 3] = fabsf(ov[k].w);
    }
  }
  __syncthreads();
  if (t < Cc){
    float v1=-1.f, v2=-1.f, v3=-1.f; int i1=0, i2=0, i3=0;
    for (int s=0; s<Ss; s++){
      float v = absb[t*Ss + s];
      if (v > v1){ v3=v2;i3=i2; v2=v1;i2=i1; v1=v;i1=s; }
      else if (v > v2){ v3=v2;i3=i2; v2=v;i2=s; }
      else if (v > v3){ v3=v;i3=s; }
    }
    float* po = out + OFF_PI + (size_t)t*Pp*3 + (size_t)p*3;
    po[0] = (float)i1; po[1] = (float)i2; po[2] = (float)i3;
  }
}

extern "C" void kernel_launch(void* const* d_in, const int* in_sizes, int n_in,
                              void* d_out, int out_size, void* d_ws, size_t ws_size,
                              hipStream_t stream){
  const float* signal = (const float*)d_in[0];
  const float* phi    = (const float*)d_in[1];
  const float* beta   = (const float*)d_in[2];
  const float* dw_w   = (const float*)d_in[3];
  const float* dw_b   = (const float*)d_in[4];
  const float* ln_w   = (const float*)d_in[5];
  const float* ln_b   = (const float*)d_in[6];
  const float* w1     = (const float*)d_in[7];
  const float* b1     = (const float*)d_in[8];
  const float* w2     = (const float*)d_in[9];
  const float* b2     = (const float*)d_in[10];
  const float* gamma  = (const float*)d_in[11];
  float* out = (float*)d_out;
  float* ws  = (float*)d_ws;

  size_t wsf = ws_size / 4;
  hipLaunchKernelGGL(k0_transpose, dim3(144), dim3(256), 0, stream, w1, w2, ws);

  if (wsf >= (size_t)WS_NEED_CHUNK){
    hipLaunchKernelGGL(k1a_dwconv, dim3(96,7), dim3(256), 0, stream,
                       signal, beta, dw_w, dw_b, ws);
    hipLaunchKernelGGL(k1_scalar, dim3(Pp), dim3(384), 0, stream,
                       signal, beta, ln_w, ln_b, b1, b2, gamma, ws, out);
  } else {
    hipLaunchKernelGGL(k1_fallback, dim3(Pp), dim3(384), 0, stream,
                       signal, beta, dw_w, dw_b, ln_w, ln_b, b1, b2, gamma, ws, out);
  }
  hipLaunchKernelGGL(k2_phiconv, dim3(96,4,4), dim3(256), 0, stream, phi, dw_w, ws, out);

  if (wsf >= (size_t)WS_NEED_FULL){
    hipLaunchKernelGGL(k0g3, dim3(Cc,8), dim3(256), 0, stream, w2, ws);
    hipLaunchKernelGGL(k3g, dim3(13*72), dim3(256), 0, stream, ws, 0, 13);
    hipLaunchKernelGGL(k3b_apply, dim3(Pp), dim3(512), 0, stream, phi, gamma, ws, out, 0);
  } else if (wsf >= (size_t)WS_NEED_CHUNK){
    hipLaunchKernelGGL(k0g3, dim3(Cc,8), dim3(256), 0, stream, w2, ws);
    for (int P0 = 0; P0 < Pp; P0 += CHUNK){
      int cp = Pp - P0; if (cp > CHUNK) cp = CHUNK;
      int mtl = (cp + 127) / 128;
      hipLaunchKernelGGL(k3g, dim3(mtl*72), dim3(256), 0, stream, ws, P0, mtl);
      hipLaunchKernelGGL(k3b_apply, dim3(cp), dim3(512), 0, stream, phi, gamma, ws, out, P0);
    }
  } else {
    hipLaunchKernelGGL(k3_heavy, dim3(Pp), dim3(256), 0, stream, phi, w1, gamma, ws, out);
  }
}